// Round 5
// baseline (2909.501 us; speedup 1.0000x reference)
//
#include <hip/hip_runtime.h>
#include <hip/hip_bf16.h>
#include <stdint.h>

#define IN_SZ 128
#define HID 128
#define OUT_SZ 67
#define SEQ 512
#define BATCH 2048

typedef __attribute__((ext_vector_type(4))) float f32x4;
typedef __attribute__((ext_vector_type(8))) short s16x8;
typedef __attribute__((ext_vector_type(8))) __bf16 bf16x8;

static __device__ __forceinline__ unsigned short f2bf(float f) {
  union { float f; uint32_t u; } c; c.f = f;
  uint32_t u = c.u;
  uint32_t r = u + 0x7FFFu + ((u >> 16) & 1u);  // RNE
  return (unsigned short)(r >> 16);
}
// packed convert: low16 = bf(lo), high16 = bf(hi)
static __device__ __forceinline__ uint32_t pk2bf(float lo, float hi) {
  __hip_bfloat162 h2 = __float22bfloat162_rn(float2{lo, hi});
  union { __hip_bfloat162 h; uint32_t u; } c; c.h = h2;
  return c.u;
}
static __device__ __forceinline__ void mfma16(f32x4& c, s16x8 a, s16x8 b) {
  c = __builtin_amdgcn_mfma_f32_16x16x32_bf16(
        __builtin_bit_cast(bf16x8, a), __builtin_bit_cast(bf16x8, b), c, 0, 0, 0);
}
// fragment k-offset for slot j (verified by R1-R4 passing): j<4 -> 4g+j ; j>=4 -> 16+4g+(j-4)
#define KOFF(g, j) (4 * (g) + ((j) & 3) + (((j) >> 2) << 4))

// ---- prep: permute Wi2o [67][128] f32 into bf16 A-fragments in ws ----
// ws layout: ws[((tile*4+kt)*64 + lane)*8 + j]
__global__ void prep_wo(const float* __restrict__ Wi2o, unsigned short* __restrict__ wsO) {
  int lane = threadIdx.x;
  int tk = blockIdx.x;             // 0..19 = tile*4+kt
  int tile = tk >> 2, kt = tk & 3;
  int g = lane >> 4, n16 = lane & 15;
  int m = 16 * tile + n16;
  unsigned short v[8];
#pragma unroll
  for (int j = 0; j < 8; ++j) {
    int k = 32 * kt + KOFF(g, j);
    float w = (m < OUT_SZ) ? Wi2o[m * HID + k] : 0.f;
    v[j] = f2bf(w);
  }
  *(s16x8*)(wsO + ((size_t)tk * 64 + lane) * 8) = *(s16x8*)v;
}

// ---- main: 1 wave per 16-batch group; h recurrence fully in registers ----
__global__ __launch_bounds__(64, 1) void rnn_kernel(
    const float* __restrict__ x, const float* __restrict__ hidden,
    const float* __restrict__ mask, const float* __restrict__ Wi2h,
    const float* __restrict__ bi2h, const unsigned short* __restrict__ wsO,
    const float* __restrict__ bi2o, float* __restrict__ Y) {

  const int lane = threadIdx.x;
  const int g = lane >> 4, n16 = lane & 15;
  const int b0 = blockIdx.x * 16;
  const float* xb = x + b0 + n16;   // + (row*SEQ + t)*BATCH

  // Wi2h A-fragments, single bf16, all 8 M-tiles in registers (256 VGPR)
  s16x8 W[8][8];
#pragma unroll
  for (int tile = 0; tile < 8; ++tile) {
    const float* wrow = Wi2h + (size_t)(16 * tile + n16) * (IN_SZ + HID);
#pragma unroll
    for (int kt = 0; kt < 8; ++kt) {
      s16x8 w8;
#pragma unroll
      for (int j = 0; j < 8; ++j)
        w8[j] = (short)f2bf(wrow[32 * kt + KOFF(g, j)]);
      W[tile][kt] = w8;
    }
  }

  // i2h bias per lane: row = 16*tile + 4g + r
  f32x4 bh[8];
#pragma unroll
  for (int tile = 0; tile < 8; ++tile)
#pragma unroll
    for (int r = 0; r < 4; ++r)
      bh[tile][r] = bi2h[16 * tile + 4 * g + r];

  // Bh = h0' = hidden*mask in B-frag layout
  s16x8 Bh[4];
#pragma unroll
  for (int kk = 0; kk < 4; ++kk) {
    s16x8 h8;
#pragma unroll
    for (int j = 0; j < 8; ++j) {
      int row = 32 * kk + KOFF(g, j);
      float hv = hidden[(size_t)row * BATCH + b0 + n16] * mask[(size_t)row * BATCH + b0 + n16];
      h8[j] = (short)f2bf(hv);
    }
    Bh[kk] = h8;
  }

  // Bx = x_0 in B-frag layout
  s16x8 Bx[4];
#pragma unroll
  for (int kt = 0; kt < 4; ++kt) {
    s16x8 x8;
#pragma unroll
    for (int j = 0; j < 8; ++j) {
      int row = 32 * kt + KOFF(g, j);
      x8[j] = (short)f2bf(xb[((size_t)row * SEQ + 0) * BATCH]);
    }
    Bx[kt] = x8;
  }

  // raw prefetch of x_1
  float xr[32];
#pragma unroll
  for (int kt = 0; kt < 4; ++kt)
#pragma unroll
    for (int j = 0; j < 8; ++j) {
      int row = 32 * kt + KOFF(g, j);
      xr[kt * 8 + j] = xb[((size_t)row * SEQ + 1) * BATCH];
    }

  for (int t = 0; t < SEQ; ++t) {
    // ---- i2h: acc[tile] = bh + Wx*Bx + Wh*Bh ; kt-outer/tile-inner = 8 independent chains
    f32x4 acc[8];
#pragma unroll
    for (int tile = 0; tile < 8; ++tile) acc[tile] = bh[tile];
#pragma unroll
    for (int kt = 0; kt < 4; ++kt)
#pragma unroll
      for (int tile = 0; tile < 8; ++tile)
        mfma16(acc[tile], W[tile][kt], Bx[kt]);
#pragma unroll
    for (int kk = 0; kk < 4; ++kk)
#pragma unroll
      for (int tile = 0; tile < 8; ++tile)
        mfma16(acc[tile], W[tile][4 + kk], Bh[kk]);

    // ---- convert x_{t+1} raws -> Bx ; issue x_{t+2} loads (off critical path)
#pragma unroll
    for (int kt = 0; kt < 4; ++kt) {
      union { s16x8 v; uint32_t d[4]; } u;
      u.d[0] = pk2bf(xr[kt * 8 + 0], xr[kt * 8 + 1]);
      u.d[1] = pk2bf(xr[kt * 8 + 2], xr[kt * 8 + 3]);
      u.d[2] = pk2bf(xr[kt * 8 + 4], xr[kt * 8 + 5]);
      u.d[3] = pk2bf(xr[kt * 8 + 6], xr[kt * 8 + 7]);
      Bx[kt] = u.v;
    }
    {
      int tn = (t + 2 < SEQ) ? t + 2 : SEQ - 1;
#pragma unroll
      for (int kt = 0; kt < 4; ++kt)
#pragma unroll
        for (int j = 0; j < 8; ++j) {
          int row = 32 * kt + KOFF(g, j);
          xr[kt * 8 + j] = xb[((size_t)row * SEQ + tn) * BATCH];
        }
    }

    // ---- tanh + repack: D-frags of tiles (2kk, 2kk+1) ARE the next B_h frag kk
#pragma unroll
    for (int kk = 0; kk < 4; ++kk) {
      float th[8];
#pragma unroll
      for (int r = 0; r < 4; ++r) {
        float e = __expf(2.f * acc[2 * kk][r]);
        th[r] = 1.f - 2.f / (e + 1.f);
      }
#pragma unroll
      for (int r = 0; r < 4; ++r) {
        float e = __expf(2.f * acc[2 * kk + 1][r]);
        th[4 + r] = 1.f - 2.f / (e + 1.f);
      }
      union { s16x8 v; uint32_t d[4]; } u;
      u.d[0] = pk2bf(th[0], th[1]);
      u.d[1] = pk2bf(th[2], th[3]);
      u.d[2] = pk2bf(th[4], th[5]);
      u.d[3] = pk2bf(th[6], th[7]);
      Bh[kk] = u.v;
    }

    // ---- i2o: Y_t = relu(Wi2o*h_t + bo) ; Wi2o frags streamed from ws (L1)
#pragma unroll
    for (int ot = 0; ot < 5; ++ot) {
      f32x4 ao = {0.f, 0.f, 0.f, 0.f};
#pragma unroll
      for (int kk = 0; kk < 4; ++kk) {
        s16x8 wf = *(const s16x8*)(wsO + ((size_t)(ot * 4 + kk) * 64 + lane) * 8);
        mfma16(ao, wf, Bh[kk]);
      }
#pragma unroll
      for (int r = 0; r < 4; ++r) {
        int m = 16 * ot + 4 * g + r;
        if (m < OUT_SZ) {
          float o = fmaxf(ao[r] + bi2o[m], 0.f);
          Y[((size_t)m * SEQ + t) * BATCH + b0 + n16] = o;
        }
      }
    }
  }
}

extern "C" void kernel_launch(void* const* d_in, const int* in_sizes, int n_in,
                              void* d_out, int out_size, void* d_ws, size_t ws_size,
                              hipStream_t stream) {
  const float* x      = (const float*)d_in[0];
  const float* hidden = (const float*)d_in[1];
  const float* mask   = (const float*)d_in[2];
  const float* Wi2h   = (const float*)d_in[3];
  const float* bi2h   = (const float*)d_in[4];
  const float* Wi2o   = (const float*)d_in[5];
  const float* bi2o   = (const float*)d_in[6];
  float* Y = (float*)d_out;
  unsigned short* wsO = (unsigned short*)d_ws;
  (void)in_sizes; (void)n_in; (void)out_size; (void)ws_size;
  prep_wo<<<dim3(20), dim3(64), 0, stream>>>(Wi2o, wsO);
  rnn_kernel<<<dim3(BATCH / 16), dim3(64), 0, stream>>>(
      x, hidden, mask, Wi2h, bi2h, wsO, bi2o, Y);
}

// Round 6
// 693.772 us; speedup vs baseline: 4.1937x; 4.1937x over previous
//
#include <hip/hip_runtime.h>
#include <hip/hip_bf16.h>
#include <stdint.h>

#define IN_SZ 128
#define HID 128
#define OUT_SZ 67
#define SEQ 512
#define BATCH 2048
#define NW 4            // waves per block (M-split by 4)
#define NTHR (NW * 64)
#define NOIDX 0xFFFFFFFFu

typedef __attribute__((ext_vector_type(4))) float f32x4;
typedef __attribute__((ext_vector_type(8))) short s16x8;
typedef __attribute__((ext_vector_type(8))) __bf16 bf16x8;

// setup-only scalar RNE
static __device__ __forceinline__ unsigned short f2bf(float f) {
  union { float f; uint32_t u; } c; c.f = f;
  uint32_t u = c.u;
  uint32_t r = u + 0x7FFFu + ((u >> 16) & 1u);
  return (unsigned short)(r >> 16);
}
// packed convert (hot loop)
static __device__ __forceinline__ uint32_t pk2bf(float lo, float hi) {
  __hip_bfloat162 h2 = __float22bfloat162_rn(float2{lo, hi});
  union { __hip_bfloat162 h; uint32_t u; } c; c.h = h2;
  return c.u;
}
static __device__ __forceinline__ void mfma16(f32x4& c, s16x8 a, s16x8 b) {
  c = __builtin_amdgcn_mfma_f32_16x16x32_bf16(
        __builtin_bit_cast(bf16x8, a), __builtin_bit_cast(bf16x8, b), c, 0, 0, 0);
}
// B/A fragment k-offset for slot j (HW-verified R1-R5)
#define KOFF(g, j) (4 * (g) + ((j) & 3) + (((j) >> 2) << 4))

// lgkm-only barrier: x loads / Y stores float across steps (no vmcnt drain)
static __device__ __forceinline__ void sync_lds() {
  __builtin_amdgcn_sched_barrier(0);
  asm volatile("s_waitcnt lgkmcnt(0)\n\ts_barrier" ::: "memory");
  __builtin_amdgcn_sched_barrier(0);
}

__global__ __launch_bounds__(NTHR, 1) void rnn_kernel(
    const float* __restrict__ x, const float* __restrict__ hidden,
    const float* __restrict__ mask, const float* __restrict__ Wi2h,
    const float* __restrict__ bi2h, const float* __restrict__ Wi2o,
    const float* __restrict__ bi2o, float* __restrict__ Y) {

  // frag store: [buf][frag 0..3 = x kt, 4..7 = h kk][lane] ; 16 KB total
  __shared__ s16x8 sF[2][8][64];

  const int tid = threadIdx.x;
  const int wave = tid >> 6;          // 0..3 ; owns M-tiles {2w, 2w+1}
  const int lane = tid & 63;
  const int g = lane >> 4;
  const int n16 = lane & 15;
  const int b0 = blockIdx.x * 16;

  // ---- Wi2h A-frags for tiles 2w, 2w+1 (single bf16; R5 proved accuracy) ----
  s16x8 WA[2][8];
#pragma unroll
  for (int tl = 0; tl < 2; ++tl) {
    const float* wrow = Wi2h + (size_t)(16 * (2 * wave + tl) + n16) * (IN_SZ + HID);
#pragma unroll
    for (int kt = 0; kt < 8; ++kt) {
      s16x8 w8;
#pragma unroll
      for (int j = 0; j < 8; ++j)
        w8[j] = (short)f2bf(wrow[32 * kt + KOFF(g, j)]);
      WA[tl][kt] = w8;
    }
  }

  // ---- Wi2o A-frags: slot0 = tile `wave`; slot1 = tile 4 (wave 0 only) ----
  const bool hasS1 = (wave == 0);
  s16x8 wO0[4], wO1[4];
#pragma unroll
  for (int kk = 0; kk < 4; ++kk) {
    s16x8 a, b;
#pragma unroll
    for (int j = 0; j < 8; ++j) {
      int m0 = 16 * wave + n16;
      a[j] = (short)f2bf((m0 < OUT_SZ) ? Wi2o[(size_t)m0 * HID + 32 * kk + KOFF(g, j)] : 0.f);
      int m1 = 64 + n16;
      b[j] = (short)((hasS1 && m1 < OUT_SZ)
                     ? f2bf(Wi2o[(size_t)m1 * HID + 32 * kk + KOFF(g, j)]) : 0);
    }
    wO0[kk] = a; wO1[kk] = b;
  }

  // ---- biases / Y offsets ----
  f32x4 bhv0, bhv1, bov0, bov1;
  uint32_t yo0[4], yo1[4];
#pragma unroll
  for (int r = 0; r < 4; ++r) {
    bhv0[r] = bi2h[16 * (2 * wave + 0) + 4 * g + r];
    bhv1[r] = bi2h[16 * (2 * wave + 1) + 4 * g + r];
    int m0 = 16 * wave + 4 * g + r;
    bov0[r] = (m0 < OUT_SZ) ? bi2o[m0] : 0.f;
    yo0[r]  = (m0 < OUT_SZ) ? (uint32_t)(m0 * SEQ * BATCH + b0 + n16) : NOIDX;
    int m1 = 64 + 4 * g + r;
    bov1[r] = (hasS1 && m1 < OUT_SZ) ? bi2o[m1] : 0.f;
    yo1[r]  = (hasS1 && m1 < OUT_SZ) ? (uint32_t)(m1 * SEQ * BATCH + b0 + n16) : NOIDX;
  }

  // ---- x row pointers for this wave's frag (rows 32w + KOFF) ----
  const float* xp[8];
  float xc[8];   // raw x_{t+1}
#pragma unroll
  for (int j = 0; j < 8; ++j) {
    int row = 32 * wave + KOFF(g, j);
    const float* base = x + (size_t)row * SEQ * BATCH + b0 + n16;
    xc[j] = base[(size_t)1 * BATCH];            // x_1
    xp[j] = base + (size_t)2 * BATCH;           // -> x_2
    // stage x_0 handled below from base[0]
  }

  // ---- stage x_0 and h_0 frags into buf 0 ----
  {
    s16x8 xf, hf;
#pragma unroll
    for (int j = 0; j < 8; j += 2) {
      int r0 = 32 * wave + KOFF(g, j), r1 = 32 * wave + KOFF(g, j + 1);
      float v0 = x[(size_t)r0 * SEQ * BATCH + b0 + n16];
      float v1 = x[(size_t)r1 * SEQ * BATCH + b0 + n16];
      uint32_t d = pk2bf(v0, v1);
      xf[j] = (short)d; xf[j + 1] = (short)(d >> 16);
      float h0 = hidden[(size_t)r0 * BATCH + b0 + n16] * mask[(size_t)r0 * BATCH + b0 + n16];
      float h1 = hidden[(size_t)r1 * BATCH + b0 + n16] * mask[(size_t)r1 * BATCH + b0 + n16];
      uint32_t e = pk2bf(h0, h1);
      hf[j] = (short)e; hf[j + 1] = (short)(e >> 16);
    }
    sF[0][wave][lane] = xf;
    sF[0][4 + wave][lane] = hf;
  }
  sync_lds();

  uint32_t toffY = 0;

  for (int t = 0; t < SEQ; ++t) {
    const int p = t & 1;

    // issue x_{t+2} loads (consumed next iter; ~2 steps of latency cover)
    float xn[8];
#pragma unroll
    for (int j = 0; j < 8; ++j) xn[j] = *xp[j];
    if (t + 3 < SEQ) {
#pragma unroll
      for (int j = 0; j < 8; ++j) xp[j] += BATCH;
    }

    // read all frags of [x_t ; h_t]
    s16x8 Bx0 = sF[p][0][lane], Bx1 = sF[p][1][lane];
    s16x8 Bx2 = sF[p][2][lane], Bx3 = sF[p][3][lane];
    s16x8 Bh0 = sF[p][4][lane], Bh1 = sF[p][5][lane];
    s16x8 Bh2 = sF[p][6][lane], Bh3 = sF[p][7][lane];

    // ---- i2h: 4 independent chains of depth 4 ----
    f32x4 a0 = bhv0, b0v = {0, 0, 0, 0};
    f32x4 a1 = bhv1, b1v = {0, 0, 0, 0};
    mfma16(a0, WA[0][0], Bx0); mfma16(b0v, WA[0][1], Bx1);
    mfma16(a1, WA[1][0], Bx0); mfma16(b1v, WA[1][1], Bx1);
    mfma16(a0, WA[0][2], Bx2); mfma16(b0v, WA[0][3], Bx3);
    mfma16(a1, WA[1][2], Bx2); mfma16(b1v, WA[1][3], Bx3);
    mfma16(a0, WA[0][4], Bh0); mfma16(b0v, WA[0][5], Bh1);
    mfma16(a1, WA[1][4], Bh0); mfma16(b1v, WA[1][5], Bh1);
    mfma16(a0, WA[0][6], Bh2); mfma16(b0v, WA[0][7], Bh3);
    mfma16(a1, WA[1][6], Bh2); mfma16(b1v, WA[1][7], Bh3);

    // ---- i2o(t-1): y_{t-1} = relu(Wo·h_t + bo) ; independent, fills stalls ----
    if (t > 0) {
      f32x4 ao = bov0;
      mfma16(ao, wO0[0], Bh0); mfma16(ao, wO0[1], Bh1);
      mfma16(ao, wO0[2], Bh2); mfma16(ao, wO0[3], Bh3);
#pragma unroll
      for (int r = 0; r < 4; ++r)
        if (yo0[r] != NOIDX) Y[(size_t)yo0[r] + toffY] = fmaxf(ao[r], 0.f);
      if (hasS1) {
        f32x4 ao1 = bov1;
        mfma16(ao1, wO1[0], Bh0); mfma16(ao1, wO1[1], Bh1);
        mfma16(ao1, wO1[2], Bh2); mfma16(ao1, wO1[3], Bh3);
#pragma unroll
        for (int r = 0; r < 4; ++r)
          if (yo1[r] != NOIDX) Y[(size_t)yo1[r] + toffY] = fmaxf(ao1[r], 0.f);
      }
      toffY += BATCH;
    }

    // ---- h_{t+1} own frag: tanh(acc) ; D-frag == B-frag (identity repack) ----
    {
      f32x4 acc0 = a0 + b0v, acc1 = a1 + b1v;
      float th[8];
#pragma unroll
      for (int r = 0; r < 4; ++r) {
        float e = __expf(2.f * acc0[r]);
        th[r] = 1.f - 2.f / (e + 1.f);
      }
#pragma unroll
      for (int r = 0; r < 4; ++r) {
        float e = __expf(2.f * acc1[r]);
        th[4 + r] = 1.f - 2.f / (e + 1.f);
      }
      union { s16x8 v; uint32_t d[4]; } u;
      u.d[0] = pk2bf(th[0], th[1]);
      u.d[1] = pk2bf(th[2], th[3]);
      u.d[2] = pk2bf(th[4], th[5]);
      u.d[3] = pk2bf(th[6], th[7]);
      sF[p ^ 1][4 + wave][lane] = u.v;
    }
    // ---- own x_{t+1} frag ----
    {
      union { s16x8 v; uint32_t d[4]; } u;
      u.d[0] = pk2bf(xc[0], xc[1]);
      u.d[1] = pk2bf(xc[2], xc[3]);
      u.d[2] = pk2bf(xc[4], xc[5]);
      u.d[3] = pk2bf(xc[6], xc[7]);
      sF[p ^ 1][wave][lane] = u.v;
    }
#pragma unroll
    for (int j = 0; j < 8; ++j) xc[j] = xn[j];

    sync_lds();   // publish buf p^1
  }

  // ---- epilogue: y_{SEQ-1} = relu(Wo·h_SEQ + bo) ; h_SEQ frags in buf 0 ----
  {
    s16x8 Bh0 = sF[0][4][lane], Bh1 = sF[0][5][lane];
    s16x8 Bh2 = sF[0][6][lane], Bh3 = sF[0][7][lane];
    f32x4 ao = bov0;
    mfma16(ao, wO0[0], Bh0); mfma16(ao, wO0[1], Bh1);
    mfma16(ao, wO0[2], Bh2); mfma16(ao, wO0[3], Bh3);
#pragma unroll
    for (int r = 0; r < 4; ++r)
      if (yo0[r] != NOIDX) Y[(size_t)yo0[r] + toffY] = fmaxf(ao[r], 0.f);
    if (hasS1) {
      f32x4 ao1 = bov1;
      mfma16(ao1, wO1[0], Bh0); mfma16(ao1, wO1[1], Bh1);
      mfma16(ao1, wO1[2], Bh2); mfma16(ao1, wO1[3], Bh3);
#pragma unroll
      for (int r = 0; r < 4; ++r)
        if (yo1[r] != NOIDX) Y[(size_t)yo1[r] + toffY] = fmaxf(ao1[r], 0.f);
    }
  }
}

extern "C" void kernel_launch(void* const* d_in, const int* in_sizes, int n_in,
                              void* d_out, int out_size, void* d_ws, size_t ws_size,
                              hipStream_t stream) {
  const float* x      = (const float*)d_in[0];
  const float* hidden = (const float*)d_in[1];
  const float* mask   = (const float*)d_in[2];
  const float* Wi2h   = (const float*)d_in[3];
  const float* bi2h   = (const float*)d_in[4];
  const float* Wi2o   = (const float*)d_in[5];
  const float* bi2o   = (const float*)d_in[6];
  float* Y = (float*)d_out;
  (void)in_sizes; (void)n_in; (void)out_size; (void)d_ws; (void)ws_size;
  rnn_kernel<<<dim3(BATCH / 16), dim3(NTHR), 0, stream>>>(
      x, hidden, mask, Wi2h, bi2h, Wi2o, bi2o, Y);
}